// Round 24
// baseline (131.049 us; speedup 1.0000x reference)
//
#include <hip/hip_runtime.h>
#include <hip/hip_bf16.h>

#define NNODES 6144
#define FIN    128
#define FOUTC  64
#define NHEAD  2
#define ALPHA  0.2f
#define LN_EPS 1e-5f
#define MASKW  192                      // u32 words per row (6144/32)
#define LOG2E  1.4426950408889634f
#define INVN   (1.0f / 6144.0f)

typedef __attribute__((ext_vector_type(4))) float f32x4;
typedef __attribute__((ext_vector_type(8))) short short8;
typedef __attribute__((ext_vector_type(4))) int   i32x4;

// f32 -> bf16 bits, round-to-nearest-even (k1 packing)
static __device__ __forceinline__ short f2bf(float x) {
    unsigned u = __float_as_uint(x);
    u = (u + 0x7fffu + ((u >> 16) & 1u)) >> 16;
    return (short)u;
}

// HW RNE f32 -> bf16 bits (compiler fuses pairs to v_cvt_pk_bf16_f32)
static __device__ __forceinline__ short f2bf_hw(float x) {
    return (short)__bfloat16_as_ushort(__float2bfloat16(x));
}

// s1,s2 PRE-SCALED by log2e. unnormalized t = 2^lrelu(e')
static __device__ __forceinline__ float ecalc2(float e, unsigned bit) {
    float m = fmaxf(e, ALPHA * e);
    return bit ? __builtin_amdgcn_exp2f(m) : 0.0f;
}
// normalized p = 2^(lrelu(e') + li), li = -log2(psum); INVN for uni rows
static __device__ __forceinline__ float pcalc2(float e, float li, unsigned bit,
                                               bool uni) {
    float m = fmaxf(e, ALPHA * e) + li;
    float t = bit ? __builtin_amdgcn_exp2f(m) : 0.0f;
    return uni ? INVN : t;
}

// K1: ht = h @ W per head; htbP pre-packed bf16 B-fragments; s1/s2 scaled by
// log2e. (proven)
__global__ __launch_bounds__(256) void gat_k1(const float* __restrict__ h,
        const float* __restrict__ W, const float* __restrict__ a,
        short* __restrict__ htbP, float* __restrict__ s1, float* __restrict__ s2) {
    __shared__ float hrow[4][FIN];
    const int wid = threadIdx.x >> 6, lane = threadIdx.x & 63;
    const int n = blockIdx.x * 4 + wid;
    hrow[wid][lane]      = h[(size_t)n * FIN + lane];
    hrow[wid][lane + 64] = h[(size_t)n * FIN + lane + 64];
    __syncthreads();
    float acc0 = 0.f, acc1 = 0.f;
    #pragma unroll 8
    for (int k = 0; k < FIN; ++k) {
        float hv = hrow[wid][k];
        acc0 = fmaf(hv, W[k * FOUTC + lane], acc0);
        acc1 = fmaf(hv, W[(FIN + k) * FOUTC + lane], acc1);
    }
    const int it_ = n >> 5, kk = n & 31;
    const int fl  = (lane & 15) + ((kk >> 3) << 4);
    const size_t pb = ((size_t)(it_ * 4 + (lane >> 4))) * 512 + fl * 8 + (kk & 7);
    htbP[pb]          = f2bf(acc0);
    htbP[393216 + pb] = f2bf(acc1);
    float r00 = acc0 * a[lane];
    float r01 = acc0 * a[FOUTC + lane];
    float r10 = acc1 * a[2 * FOUTC + lane];
    float r11 = acc1 * a[3 * FOUTC + lane];
    #pragma unroll
    for (int off = 32; off; off >>= 1) {
        r00 += __shfl_xor(r00, off);
        r01 += __shfl_xor(r01, off);
        r10 += __shfl_xor(r10, off);
        r11 += __shfl_xor(r11, off);
    }
    if (lane == 0) {
        s1[n] = r00 * LOG2E;          s2[n] = r01 * LOG2E;
        s1[NNODES + n] = r10 * LOG2E; s2[NNODES + n] = r11 * LOG2E;
    }
}

// K0: PURE adj->bitmask pack. Streams adj once (plain loads, R23-proven);
// minimal VALU per 16B: 4 compares + 3 shfl-ORs. Should run at stream rate.
__global__ __launch_bounds__(256) void gat_k0(const int* __restrict__ adj,
        unsigned* __restrict__ mask32) {
    const int n = blockIdx.x;
    const int t = threadIdx.x;
    const int wid = t >> 6, lane = t & 63;
    const i32x4* arow = (const i32x4*)(adj + (size_t)n * NNODES);
    unsigned* mrow = mask32 + (size_t)n * MASKW;
    #pragma unroll
    for (int i = 0; i < 6; ++i) {
        i32x4 av = arow[t + i * 256];
        unsigned nib = (unsigned)(av[0] > 0) | ((unsigned)(av[1] > 0) << 1)
                     | ((unsigned)(av[2] > 0) << 2) | ((unsigned)(av[3] > 0) << 3);
        unsigned v = nib << ((lane & 7) * 4);
        v |= (unsigned)__shfl_xor((int)v, 1);
        v |= (unsigned)__shfl_xor((int)v, 2);
        v |= (unsigned)__shfl_xor((int)v, 4);
        if ((lane & 7) == 0)
            mrow[i * 32 + wid * 8 + (lane >> 3)] = v;
    }
}

// K2b: psum from mask32 (4.7 MB, L2-resident) + s2 — no adj re-read.
// Thread t, iter i covers cols 4t+1024i: nibble from word 32i + (t>>3).
__global__ __launch_bounds__(256) void gat_k2b(const unsigned* __restrict__ mask32,
        const float* __restrict__ s1, const float* __restrict__ s2,
        float* __restrict__ psum) {
    const int n = blockIdx.x;
    const int t = threadIdx.x;
    const int wid = t >> 6, lane = t & 63;
    const float4* s2h0 = (const float4*)(s2);
    const float4* s2h1 = (const float4*)(s2 + NNODES);
    const float s10 = s1[n], s11 = s1[NNODES + n];
    const unsigned* mrow = mask32 + (size_t)n * MASKW;
    const int sh = (t & 7) * 4;
    float sum0 = 0.f, sum1 = 0.f;
    #pragma unroll
    for (int i = 0; i < 6; ++i) {
        const int c4 = t + i * 256;
        const unsigned nib = (mrow[i * 32 + (t >> 3)] >> sh) & 0xfu;
        float4 sa = s2h0[c4];
        float4 sb = s2h1[c4];
        sum0 += (ecalc2(s10 + sa.x, nib & 1u) + ecalc2(s10 + sa.y, nib & 2u))
              + (ecalc2(s10 + sa.z, nib & 4u) + ecalc2(s10 + sa.w, nib & 8u));
        sum1 += (ecalc2(s11 + sb.x, nib & 1u) + ecalc2(s11 + sb.y, nib & 2u))
              + (ecalc2(s11 + sb.z, nib & 4u) + ecalc2(s11 + sb.w, nib & 8u));
    }
    #pragma unroll
    for (int off = 32; off; off >>= 1) {
        sum0 += __shfl_xor(sum0, off);
        sum1 += __shfl_xor(sum1, off);
    }
    __shared__ float red[2][4];
    if (lane == 0) { red[0][wid] = sum0; red[1][wid] = sum1; }
    __syncthreads();
    if (t == 0) {
        psum[n]          = (red[0][0] + red[0][1]) + (red[0][2] + red[0][3]);
        psum[NNODES + n] = (red[1][0] + red[1][1]) + (red[1][2] + red[1][3]);
    }
}

// M-ONLY fused kernel: exp computed ONCE per element (exp2, normalize folded
// into exponent), feeds MFMA AND att via wave-private LDS transpose -> 16
// contiguous 1KB nt stores per 256-col tile. (R21-measured: ~62 µs, 5 TB/s)
template <int ITERS>
__global__ __launch_bounds__(256) void gat_m(const unsigned* __restrict__ mask32,
        const short* __restrict__ htbP, const float* __restrict__ s1,
        const float* __restrict__ s2, const float* __restrict__ psum,
        float* __restrict__ att, float* __restrict__ hpp) {
    __shared__ float stg[4][16][260];          // 260 f32 row stride
    const int w = threadIdx.x >> 6, lane = threadIdx.x & 63;
    const int hh = w & 1, cs = w >> 1;
    const int pc = blockIdx.x * 2 + cs;        // col chunk
    const int n0 = blockIdx.y * 16;
    const int r = lane & 15, g = lane >> 4;
    const int node = n0 + r;
    const float s1v = s1[hh * NNODES + node];
    const float ps  = psum[hh * NNODES + node];
    const bool uni = !(ps > 0.f);
    const float li = uni ? 0.f : -__log2f(ps);
    const float* s2h = s2 + hh * NNODES;
    const unsigned* mrow = mask32 + (size_t)node * MASKW + pc * ITERS;
    const short* bb = htbP + (size_t)(hh * 192 + pc * ITERS) * 2048 + (size_t)lane * 8;
    const int cbase = pc * ITERS * 32;
    float* atth = att + (size_t)hh * NNODES * NNODES;
    float (*myst)[260] = stg[w];

    f32x4 acc0 = {0.f,0.f,0.f,0.f}, acc1 = {0.f,0.f,0.f,0.f};
    f32x4 acc2 = {0.f,0.f,0.f,0.f}, acc3 = {0.f,0.f,0.f,0.f};

    for (int it = 0; it < ITERS; ++it) {
        const int kb = cbase + it * 32 + g * 8;
        const unsigned mb = (mrow[it] >> (g * 8)) & 0xffu;
        float4 sa = *(const float4*)(s2h + kb);
        float4 sb = *(const float4*)(s2h + kb + 4);
        float p0 = pcalc2(s1v + sa.x, li, mb & 1u,   uni);
        float p1 = pcalc2(s1v + sa.y, li, mb & 2u,   uni);
        float p2 = pcalc2(s1v + sa.z, li, mb & 4u,   uni);
        float p3 = pcalc2(s1v + sa.w, li, mb & 8u,   uni);
        float p4 = pcalc2(s1v + sb.x, li, mb & 16u,  uni);
        float p5 = pcalc2(s1v + sb.y, li, mb & 32u,  uni);
        float p6 = pcalc2(s1v + sb.z, li, mb & 64u,  uni);
        float p7 = pcalc2(s1v + sb.w, li, mb & 128u, uni);
        // stage normalized f32 p into wave-private LDS (exact att values)
        float* sp = &myst[r][(it & 7) * 32 + g * 8];
        *(f32x4*)(sp)     = f32x4{p0, p1, p2, p3};
        *(f32x4*)(sp + 4) = f32x4{p4, p5, p6, p7};
        short8 af = { f2bf_hw(p0), f2bf_hw(p1), f2bf_hw(p2), f2bf_hw(p3),
                      f2bf_hw(p4), f2bf_hw(p5), f2bf_hw(p6), f2bf_hw(p7) };
        const short* bp = bb + (size_t)it * 2048;
        short8 b0 = *(const short8*)(bp);
        short8 b1 = *(const short8*)(bp + 512);
        short8 b2 = *(const short8*)(bp + 1024);
        short8 b3 = *(const short8*)(bp + 1536);
        acc0 = __builtin_amdgcn_mfma_f32_16x16x32_bf16(af, b0, acc0, 0, 0, 0);
        acc1 = __builtin_amdgcn_mfma_f32_16x16x32_bf16(af, b1, acc1, 0, 0, 0);
        acc2 = __builtin_amdgcn_mfma_f32_16x16x32_bf16(af, b2, acc2, 0, 0, 0);
        acc3 = __builtin_amdgcn_mfma_f32_16x16x32_bf16(af, b3, acc3, 0, 0, 0);
        if ((it & 7) == 7) {
            // flush 16 rows x 256 cols: one contiguous 1KB nt store per row
            const int colbase = cbase + (it - 7) * 32;
            #pragma unroll 4
            for (int rr = 0; rr < 16; ++rr) {
                f32x4 v = *(const f32x4*)&myst[rr][4 * lane];
                __builtin_nontemporal_store(v,
                    (f32x4*)(atth + (size_t)(n0 + rr) * NNODES + colbase + 4 * lane));
            }
        }
    }
    // A normalized in-loop -> acc is final hp partial (R5 semantics)
    float* hb = hpp + ((size_t)(pc * NHEAD + hh) * NNODES + (n0 + g * 4)) * FOUTC + r;
    #pragma unroll
    for (int reg = 0; reg < 4; ++reg) {
        hb[(size_t)reg * FOUTC +  0] = acc0[reg];
        hb[(size_t)reg * FOUTC + 16] = acc1[reg];
        hb[(size_t)reg * FOUTC + 32] = acc2[reg];
        hb[(size_t)reg * FOUTC + 48] = acc3[reg];
    }
}

// K4: sum nchunk hp partials per head, layernorm over 128 features, write out
__global__ __launch_bounds__(256) void gat_k4(const float* __restrict__ hpp,
        const float* __restrict__ gamma, const float* __restrict__ beta,
        float* __restrict__ out, int nchunk) {
    const int wid = threadIdx.x >> 6, lane = threadIdx.x & 63;
    const int n = blockIdx.x * 4 + wid;
    float v0 = 0.f, v1 = 0.f;
    for (int p = 0; p < nchunk; ++p) {
        v0 += hpp[((size_t)(p * NHEAD + 0) * NNODES + n) * FOUTC + lane];
        v1 += hpp[((size_t)(p * NHEAD + 1) * NNODES + n) * FOUTC + lane];
    }
    float s = v0 + v1;
    #pragma unroll
    for (int off = 32; off; off >>= 1) s += __shfl_xor(s, off);
    const float mu = s * (1.0f / 128.0f);
    const float d0 = v0 - mu, d1 = v1 - mu;
    float q = d0 * d0 + d1 * d1;
    #pragma unroll
    for (int off = 32; off; off >>= 1) q += __shfl_xor(q, off);
    const float rstd = 1.0f / sqrtf(q * (1.0f / 128.0f) + LN_EPS);
    out[(size_t)n * 128 + lane]      = d0 * rstd * gamma[lane] + beta[lane];
    out[(size_t)n * 128 + 64 + lane] = d1 * rstd * gamma[64 + lane] + beta[64 + lane];
}

extern "C" void kernel_launch(void* const* d_in, const int* in_sizes, int n_in,
                              void* d_out, int out_size, void* d_ws, size_t ws_size,
                              hipStream_t stream) {
    const float* h     = (const float*)d_in[0];
    const int*   adj   = (const int*)d_in[1];
    const float* W     = (const float*)d_in[2];
    const float* a     = (const float*)d_in[3];
    const float* gamma = (const float*)d_in[4];
    const float* beta  = (const float*)d_in[5];
    float* out = (float*)d_out;
    float* att = out + (size_t)NNODES * (NHEAD * FOUTC);   // out first, then att

    char* ws = (char*)d_ws;
    short* htbP = (short*)ws;                               // 1,572,864 B
    float* s1   = (float*)(ws + 1572864);                   // 49,152 B
    float* s2p  = (float*)(ws + 1572864 + 49152);           // 49,152 B
    float* psum = (float*)(ws + 1572864 + 2 * 49152);       // 49,152 B
    unsigned* mask32 = (unsigned*)(ws + 1572864 + 3 * 49152);        // 4,718,592 B
    char* hpp_base = ws + 1572864 + 3 * 49152 + 4718592;             // = 6,438,912
    size_t avail = (ws_size > 6438912) ? ws_size - 6438912 : 0;
    const size_t per_chunk = (size_t)NHEAD * NNODES * FOUTC * 4;     // 3,145,728 B
    int nchunk = 2;
    if (avail >= 8 * per_chunk)      nchunk = 8;
    else if (avail >= 4 * per_chunk) nchunk = 4;
    float* hpp = (float*)hpp_base;

    gat_k1<<<NNODES / 4, 256, 0, stream>>>(h, W, a, htbP, s1, s2p);
    gat_k0<<<NNODES, 256, 0, stream>>>(adj, mask32);
    gat_k2b<<<NNODES, 256, 0, stream>>>(mask32, s1, s2p, psum);
    dim3 gm(nchunk / 2, NNODES / 16);
    if (nchunk == 8)
        gat_m<24><<<gm, 256, 0, stream>>>(mask32, htbP, s1, s2p, psum, att, hpp);
    else if (nchunk == 4)
        gat_m<48><<<gm, 256, 0, stream>>>(mask32, htbP, s1, s2p, psum, att, hpp);
    else
        gat_m<96><<<gm, 256, 0, stream>>>(mask32, htbP, s1, s2p, psum, att, hpp);
    gat_k4<<<NNODES / 4, 256, 0, stream>>>(hpp, gamma, beta, out, nchunk);
}

// Round 25
// 117.171 us; speedup vs baseline: 1.1184x; 1.1184x over previous
//
#include <hip/hip_runtime.h>
#include <hip/hip_bf16.h>

#define NNODES 6144
#define FIN    128
#define FOUTC  64
#define NHEAD  2
#define ALPHA  0.2f
#define LN_EPS 1e-5f
#define MASKW  192                      // u32 words per row (6144/32)
#define LOG2E  1.4426950408889634f
#define INVN   (1.0f / 6144.0f)

typedef __attribute__((ext_vector_type(4))) float f32x4;
typedef __attribute__((ext_vector_type(8))) short short8;
typedef __attribute__((ext_vector_type(4))) int   i32x4;

// f32 -> bf16 bits, round-to-nearest-even (k1 packing)
static __device__ __forceinline__ short f2bf(float x) {
    unsigned u = __float_as_uint(x);
    u = (u + 0x7fffu + ((u >> 16) & 1u)) >> 16;
    return (short)u;
}

// HW RNE f32 -> bf16 bits (compiler fuses pairs to v_cvt_pk_bf16_f32)
static __device__ __forceinline__ short f2bf_hw(float x) {
    return (short)__bfloat16_as_ushort(__float2bfloat16(x));
}

// s1,s2 PRE-SCALED by log2e (lrelu commutes with positive scale).
// unnormalized t = 2^lrelu(e')
static __device__ __forceinline__ float ecalc2(float e, unsigned bit) {
    float m = fmaxf(e, ALPHA * e);
    return bit ? __builtin_amdgcn_exp2f(m) : 0.0f;
}
// normalized p = 2^(lrelu(e') + li), li = -log2(psum); INVN for uni rows
static __device__ __forceinline__ float pcalc2(float e, float li, unsigned bit,
                                               bool uni) {
    float m = fmaxf(e, ALPHA * e) + li;
    float t = bit ? __builtin_amdgcn_exp2f(m) : 0.0f;
    return uni ? INVN : t;
}

// K1: ht = h @ W per head; htbP pre-packed bf16 B-fragments; s1/s2 scaled by
// log2e. (proven)
__global__ __launch_bounds__(256) void gat_k1(const float* __restrict__ h,
        const float* __restrict__ W, const float* __restrict__ a,
        short* __restrict__ htbP, float* __restrict__ s1, float* __restrict__ s2) {
    __shared__ float hrow[4][FIN];
    const int wid = threadIdx.x >> 6, lane = threadIdx.x & 63;
    const int n = blockIdx.x * 4 + wid;
    hrow[wid][lane]      = h[(size_t)n * FIN + lane];
    hrow[wid][lane + 64] = h[(size_t)n * FIN + lane + 64];
    __syncthreads();
    float acc0 = 0.f, acc1 = 0.f;
    #pragma unroll 8
    for (int k = 0; k < FIN; ++k) {
        float hv = hrow[wid][k];
        acc0 = fmaf(hv, W[k * FOUTC + lane], acc0);
        acc1 = fmaf(hv, W[(FIN + k) * FOUTC + lane], acc1);
    }
    const int it_ = n >> 5, kk = n & 31;
    const int fl  = (lane & 15) + ((kk >> 3) << 4);
    const size_t pb = ((size_t)(it_ * 4 + (lane >> 4))) * 512 + fl * 8 + (kk & 7);
    htbP[pb]          = f2bf(acc0);
    htbP[393216 + pb] = f2bf(acc1);
    float r00 = acc0 * a[lane];
    float r01 = acc0 * a[FOUTC + lane];
    float r10 = acc1 * a[2 * FOUTC + lane];
    float r11 = acc1 * a[3 * FOUTC + lane];
    #pragma unroll
    for (int off = 32; off; off >>= 1) {
        r00 += __shfl_xor(r00, off);
        r01 += __shfl_xor(r01, off);
        r10 += __shfl_xor(r10, off);
        r11 += __shfl_xor(r11, off);
    }
    if (lane == 0) {
        s1[n] = r00 * LOG2E;          s2[n] = r01 * LOG2E;
        s1[NNODES + n] = r10 * LOG2E; s2[NNODES + n] = r11 * LOG2E;
    }
}

// K2a: psum + bitmask (exp2 path), adj loads PLAIN (R23-proven: nt loads
// throttled the cold HBM stream; plain = -9.4 µs).
__global__ __launch_bounds__(256) void gat_k2a(const int* __restrict__ adj,
        const float* __restrict__ s1, const float* __restrict__ s2,
        float* __restrict__ psum, unsigned* __restrict__ mask32) {
    const int n = blockIdx.x;
    const int t = threadIdx.x;
    const int wid = t >> 6, lane = t & 63;
    const i32x4* arow = (const i32x4*)(adj + (size_t)n * NNODES);
    const float4* s2h0 = (const float4*)(s2);
    const float4* s2h1 = (const float4*)(s2 + NNODES);
    const float s10 = s1[n], s11 = s1[NNODES + n];
    float sum0 = 0.f, sum1 = 0.f;
    unsigned* mrow = mask32 + (size_t)n * MASKW;
    #pragma unroll
    for (int i = 0; i < 6; ++i) {
        int c4 = t + i * 256;
        i32x4 av = arow[c4];                 // plain load
        float4 sa = s2h0[c4];
        float4 sb = s2h1[c4];
        unsigned nib = (unsigned)(av[0] > 0) | ((unsigned)(av[1] > 0) << 1)
                     | ((unsigned)(av[2] > 0) << 2) | ((unsigned)(av[3] > 0) << 3);
        sum0 += (ecalc2(s10 + sa.x, nib & 1u) + ecalc2(s10 + sa.y, nib & 2u))
              + (ecalc2(s10 + sa.z, nib & 4u) + ecalc2(s10 + sa.w, nib & 8u));
        sum1 += (ecalc2(s11 + sb.x, nib & 1u) + ecalc2(s11 + sb.y, nib & 2u))
              + (ecalc2(s11 + sb.z, nib & 4u) + ecalc2(s11 + sb.w, nib & 8u));
        unsigned v = nib << ((lane & 7) * 4);
        v |= (unsigned)__shfl_xor((int)v, 1);
        v |= (unsigned)__shfl_xor((int)v, 2);
        v |= (unsigned)__shfl_xor((int)v, 4);
        if ((lane & 7) == 0)
            mrow[i * 32 + wid * 8 + (lane >> 3)] = v;
    }
    #pragma unroll
    for (int off = 32; off; off >>= 1) {
        sum0 += __shfl_xor(sum0, off);
        sum1 += __shfl_xor(sum1, off);
    }
    __shared__ float red[2][4];
    if (lane == 0) { red[0][wid] = sum0; red[1][wid] = sum1; }
    __syncthreads();
    if (t == 0) {
        psum[n]          = (red[0][0] + red[0][1]) + (red[0][2] + red[0][3]);
        psum[NNODES + n] = (red[1][0] + red[1][1]) + (red[1][2] + red[1][3]);
    }
}

// M-ONLY fused kernel: exp computed ONCE per element (exp2, normalize folded
// into exponent), feeds MFMA AND att via wave-private LDS transpose -> 16
// contiguous 1KB nt stores per 256-col tile. (R21-measured: ~62 µs, 5 TB/s)
template <int ITERS>
__global__ __launch_bounds__(256) void gat_m(const unsigned* __restrict__ mask32,
        const short* __restrict__ htbP, const float* __restrict__ s1,
        const float* __restrict__ s2, const float* __restrict__ psum,
        float* __restrict__ att, float* __restrict__ hpp) {
    __shared__ float stg[4][16][260];          // 260 f32 row stride
    const int w = threadIdx.x >> 6, lane = threadIdx.x & 63;
    const int hh = w & 1, cs = w >> 1;
    const int pc = blockIdx.x * 2 + cs;        // col chunk
    const int n0 = blockIdx.y * 16;
    const int r = lane & 15, g = lane >> 4;
    const int node = n0 + r;
    const float s1v = s1[hh * NNODES + node];
    const float ps  = psum[hh * NNODES + node];
    const bool uni = !(ps > 0.f);
    const float li = uni ? 0.f : -__log2f(ps);
    const float* s2h = s2 + hh * NNODES;
    const unsigned* mrow = mask32 + (size_t)node * MASKW + pc * ITERS;
    const short* bb = htbP + (size_t)(hh * 192 + pc * ITERS) * 2048 + (size_t)lane * 8;
    const int cbase = pc * ITERS * 32;
    float* atth = att + (size_t)hh * NNODES * NNODES;
    float (*myst)[260] = stg[w];

    f32x4 acc0 = {0.f,0.f,0.f,0.f}, acc1 = {0.f,0.f,0.f,0.f};
    f32x4 acc2 = {0.f,0.f,0.f,0.f}, acc3 = {0.f,0.f,0.f,0.f};

    for (int it = 0; it < ITERS; ++it) {
        const int kb = cbase + it * 32 + g * 8;
        const unsigned mb = (mrow[it] >> (g * 8)) & 0xffu;
        float4 sa = *(const float4*)(s2h + kb);
        float4 sb = *(const float4*)(s2h + kb + 4);
        float p0 = pcalc2(s1v + sa.x, li, mb & 1u,   uni);
        float p1 = pcalc2(s1v + sa.y, li, mb & 2u,   uni);
        float p2 = pcalc2(s1v + sa.z, li, mb & 4u,   uni);
        float p3 = pcalc2(s1v + sa.w, li, mb & 8u,   uni);
        float p4 = pcalc2(s1v + sb.x, li, mb & 16u,  uni);
        float p5 = pcalc2(s1v + sb.y, li, mb & 32u,  uni);
        float p6 = pcalc2(s1v + sb.z, li, mb & 64u,  uni);
        float p7 = pcalc2(s1v + sb.w, li, mb & 128u, uni);
        // stage normalized f32 p into wave-private LDS (exact att values)
        float* sp = &myst[r][(it & 7) * 32 + g * 8];
        *(f32x4*)(sp)     = f32x4{p0, p1, p2, p3};
        *(f32x4*)(sp + 4) = f32x4{p4, p5, p6, p7};
        short8 af = { f2bf_hw(p0), f2bf_hw(p1), f2bf_hw(p2), f2bf_hw(p3),
                      f2bf_hw(p4), f2bf_hw(p5), f2bf_hw(p6), f2bf_hw(p7) };
        const short* bp = bb + (size_t)it * 2048;
        short8 b0 = *(const short8*)(bp);
        short8 b1 = *(const short8*)(bp + 512);
        short8 b2 = *(const short8*)(bp + 1024);
        short8 b3 = *(const short8*)(bp + 1536);
        acc0 = __builtin_amdgcn_mfma_f32_16x16x32_bf16(af, b0, acc0, 0, 0, 0);
        acc1 = __builtin_amdgcn_mfma_f32_16x16x32_bf16(af, b1, acc1, 0, 0, 0);
        acc2 = __builtin_amdgcn_mfma_f32_16x16x32_bf16(af, b2, acc2, 0, 0, 0);
        acc3 = __builtin_amdgcn_mfma_f32_16x16x32_bf16(af, b3, acc3, 0, 0, 0);
        if ((it & 7) == 7) {
            // flush 16 rows x 256 cols: one contiguous 1KB nt store per row
            const int colbase = cbase + (it - 7) * 32;
            #pragma unroll 4
            for (int rr = 0; rr < 16; ++rr) {
                f32x4 v = *(const f32x4*)&myst[rr][4 * lane];
                __builtin_nontemporal_store(v,
                    (f32x4*)(atth + (size_t)(n0 + rr) * NNODES + colbase + 4 * lane));
            }
        }
    }
    // A normalized in-loop -> acc is final hp partial (R5 semantics)
    float* hb = hpp + ((size_t)(pc * NHEAD + hh) * NNODES + (n0 + g * 4)) * FOUTC + r;
    #pragma unroll
    for (int reg = 0; reg < 4; ++reg) {
        hb[(size_t)reg * FOUTC +  0] = acc0[reg];
        hb[(size_t)reg * FOUTC + 16] = acc1[reg];
        hb[(size_t)reg * FOUTC + 32] = acc2[reg];
        hb[(size_t)reg * FOUTC + 48] = acc3[reg];
    }
}

// K4: sum nchunk hp partials per head, layernorm over 128 features, write out
__global__ __launch_bounds__(256) void gat_k4(const float* __restrict__ hpp,
        const float* __restrict__ gamma, const float* __restrict__ beta,
        float* __restrict__ out, int nchunk) {
    const int wid = threadIdx.x >> 6, lane = threadIdx.x & 63;
    const int n = blockIdx.x * 4 + wid;
    float v0 = 0.f, v1 = 0.f;
    for (int p = 0; p < nchunk; ++p) {
        v0 += hpp[((size_t)(p * NHEAD + 0) * NNODES + n) * FOUTC + lane];
        v1 += hpp[((size_t)(p * NHEAD + 1) * NNODES + n) * FOUTC + lane];
    }
    float s = v0 + v1;
    #pragma unroll
    for (int off = 32; off; off >>= 1) s += __shfl_xor(s, off);
    const float mu = s * (1.0f / 128.0f);
    const float d0 = v0 - mu, d1 = v1 - mu;
    float q = d0 * d0 + d1 * d1;
    #pragma unroll
    for (int off = 32; off; off >>= 1) q += __shfl_xor(q, off);
    const float rstd = 1.0f / sqrtf(q * (1.0f / 128.0f) + LN_EPS);
    out[(size_t)n * 128 + lane]      = d0 * rstd * gamma[lane] + beta[lane];
    out[(size_t)n * 128 + 64 + lane] = d1 * rstd * gamma[64 + lane] + beta[64 + lane];
}

extern "C" void kernel_launch(void* const* d_in, const int* in_sizes, int n_in,
                              void* d_out, int out_size, void* d_ws, size_t ws_size,
                              hipStream_t stream) {
    const float* h     = (const float*)d_in[0];
    const int*   adj   = (const int*)d_in[1];
    const float* W     = (const float*)d_in[2];
    const float* a     = (const float*)d_in[3];
    const float* gamma = (const float*)d_in[4];
    const float* beta  = (const float*)d_in[5];
    float* out = (float*)d_out;
    float* att = out + (size_t)NNODES * (NHEAD * FOUTC);   // out first, then att

    char* ws = (char*)d_ws;
    short* htbP = (short*)ws;                               // 1,572,864 B
    float* s1   = (float*)(ws + 1572864);                   // 49,152 B
    float* s2p  = (float*)(ws + 1572864 + 49152);           // 49,152 B
    float* psum = (float*)(ws + 1572864 + 2 * 49152);       // 49,152 B
    unsigned* mask32 = (unsigned*)(ws + 1572864 + 3 * 49152);        // 4,718,592 B
    char* hpp_base = ws + 1572864 + 3 * 49152 + 4718592;             // = 6,438,912
    size_t avail = (ws_size > 6438912) ? ws_size - 6438912 : 0;
    const size_t per_chunk = (size_t)NHEAD * NNODES * FOUTC * 4;     // 3,145,728 B
    int nchunk = 2;
    if (avail >= 8 * per_chunk)      nchunk = 8;
    else if (avail >= 4 * per_chunk) nchunk = 4;
    float* hpp = (float*)hpp_base;

    gat_k1<<<NNODES / 4, 256, 0, stream>>>(h, W, a, htbP, s1, s2p);
    gat_k2a<<<NNODES, 256, 0, stream>>>(adj, s1, s2p, psum, mask32);
    dim3 gm(nchunk / 2, NNODES / 16);
    if (nchunk == 8)
        gat_m<24><<<gm, 256, 0, stream>>>(mask32, htbP, s1, s2p, psum, att, hpp);
    else if (nchunk == 4)
        gat_m<48><<<gm, 256, 0, stream>>>(mask32, htbP, s1, s2p, psum, att, hpp);
    else
        gat_m<96><<<gm, 256, 0, stream>>>(mask32, htbP, s1, s2p, psum, att, hpp);
    gat_k4<<<NNODES / 4, 256, 0, stream>>>(hpp, gamma, beta, out, nchunk);
}